// Round 4
// baseline (1809.843 us; speedup 1.0000x reference)
//
#include <hip/hip_runtime.h>
#include <hip/hip_bf16.h>
#include <math.h>

typedef __hip_bfloat16 bf16;
typedef short bf16x8 __attribute__((ext_vector_type(8)));
typedef float f32x4 __attribute__((ext_vector_type(4)));

#define BQ 128   // batch
#define TT 20    // timesteps
#define RR 49    // regions
#define DD 2048  // feature dim
#define EE 512   // embed dim
#define HH 512   // hidden
#define VV 10000 // vocab
#define XW 3072  // xcat width = E + D + H
constexpr float EPSV = 1e-5f;
#define APITCH 40  // LDS row pitch in bf16 elems (80B) — breaks pow2 bank stride

__device__ __forceinline__ float sigmoidf(float x) { return 1.f / (1.f + __expf(-x)); }
__device__ __forceinline__ float tanh_fast(float x) {
  float e = __expf(2.f * x);
  return 1.f - 2.f / (e + 1.f);
}
__device__ __forceinline__ bf16 f2b(float v) { return __float2bfloat16(v); }
__device__ __forceinline__ float b2f(bf16 v) { return __bfloat162float(v); }

// ---------------- MFMA GEMM (prologue only) ----------------
// C[M,N] = A[M,K] @ W[N,K]^T + bias. A,W bf16 K-contiguous.
// transC: store Cf[gn*ldc + row] instead of Cf[row*ldc + gn].
__global__ __launch_bounds__(256) void gemm_mfma(
    const bf16* __restrict__ A, const bf16* __restrict__ W,
    const float* __restrict__ bias,
    float* __restrict__ Cf, bf16* __restrict__ Cb, bf16* __restrict__ Cb2,
    long ldc, long ldc2, int N, int K, int act, int transC) {
  __shared__ __align__(16) short Alds[128 * APITCH];
  __shared__ __align__(16) short Wlds[64 * APITCH];
  int tid = threadIdx.x;
  int bm = blockIdx.y * 128, bn = blockIdx.x * 64;
  int w = tid >> 6, l = tid & 63;
  int lr = l & 15, lq = l >> 4;              // C col / k-quad
  int srow = tid >> 2, skq = (tid & 3) * 8;  // staging row / k-offset
  const bf16* pa0 = A + (long)(bm + srow) * K + skq;
  const bf16* pa1 = pa0 + (long)64 * K;
  const bf16* pw = W + (long)(bn + srow) * K + skq;
  bool wok = (bn + srow) < N;
  f32x4 acc[2][4] = {};
  uint4 ra0 = *(const uint4*)pa0;
  uint4 ra1 = *(const uint4*)pa1;
  uint4 rw = wok ? *(const uint4*)pw : make_uint4(0, 0, 0, 0);
  for (int k0 = 0; k0 < K; k0 += 32) {
    __syncthreads();
    *(uint4*)&Alds[srow * APITCH + skq] = ra0;
    *(uint4*)&Alds[(srow + 64) * APITCH + skq] = ra1;
    *(uint4*)&Wlds[srow * APITCH + skq] = rw;
    if (k0 + 32 < K) {
      ra0 = *(const uint4*)(pa0 + k0 + 32);
      ra1 = *(const uint4*)(pa1 + k0 + 32);
      rw = wok ? *(const uint4*)(pw + k0 + 32) : make_uint4(0, 0, 0, 0);
    }
    __syncthreads();
    bf16x8 af[2], bfr[4];
#pragma unroll
    for (int mt = 0; mt < 2; ++mt)
      af[mt] = *(const bf16x8*)&Alds[(w * 32 + mt * 16 + lr) * APITCH + lq * 8];
#pragma unroll
    for (int nt = 0; nt < 4; ++nt)
      bfr[nt] = *(const bf16x8*)&Wlds[(nt * 16 + lr) * APITCH + lq * 8];
#pragma unroll
    for (int mt = 0; mt < 2; ++mt)
#pragma unroll
      for (int nt = 0; nt < 4; ++nt)
        acc[mt][nt] = __builtin_amdgcn_mfma_f32_16x16x32_bf16(
            af[mt], bfr[nt], acc[mt][nt], 0, 0, 0);
  }
#pragma unroll
  for (int mt = 0; mt < 2; ++mt) {
    int gm = bm + w * 32 + mt * 16 + lq * 4;
#pragma unroll
    for (int nt = 0; nt < 4; ++nt) {
      int gn = bn + nt * 16 + lr;
      if (gn >= N) continue;
      float bv = bias ? bias[gn] : 0.f;
#pragma unroll
      for (int i = 0; i < 4; ++i) {
        float v = acc[mt][nt][i] + bv;
        if (act) v = fmaxf(v, 0.f);
        long row = gm + i;
        if (Cf) {
          if (transC) Cf[(long)gn * ldc + row] = v;
          else Cf[row * ldc + gn] = v;
        }
        if (Cb) Cb[row * ldc + gn] = f2b(v);
        if (Cb2) Cb2[row * ldc2 + gn] = f2b(v);
      }
    }
  }
}

// ---------------- small kernels ----------------
// mean over R regions (bf16 in) -> bf16 [B,D]
__global__ void mean_kernel(const bf16* __restrict__ feat, bf16* __restrict__ meanbf) {
  int idx = blockIdx.x * blockDim.x + threadIdx.x;
  if (idx >= BQ * DD) return;
  int b = idx / DD, d = idx - b * DD;
  const bf16* p = feat + (long)b * RR * DD + d;
  float s = 0.f;
  for (int r = 0; r < RR; ++r) s += b2f(p[(long)r * DD]);
  meanbf[idx] = f2b(s * (1.f / RR));
}

// fp32 -> bf16, 4 elems/thread
__global__ void f2b_kernel(const float* __restrict__ src, bf16* __restrict__ dst, long n4) {
  long i = (long)blockIdx.x * blockDim.x + threadIdx.x;
  if (i >= n4) return;
  float4 v = ((const float4*)src)[i];
  bf16 o[4] = {f2b(v.x), f2b(v.y), f2b(v.z), f2b(v.w)};
  *(ushort4*)(dst + i * 4) = *(const ushort4*)o;
}

// pack [W_ih | W_hh] -> Wcat bf16 [2048][3072], rows REORDERED to 4*ch+gate
// so each 64-wide N tile holds all 4 gates of 16 hidden channels.
__global__ void wcat_kernel(const float* __restrict__ W_ih, const float* __restrict__ W_hh,
                            bf16* __restrict__ Wcat) {
  int n = blockIdx.y;                 // output row, reordered space
  int src = (n & 3) * HH + (n >> 2);  // gate*512 + ch
  int kc = (blockIdx.x * blockDim.x + threadIdx.x) * 4;
  float4 v = (kc < EE + DD) ? *(const float4*)(W_ih + (long)src * (EE + DD) + kc)
                            : *(const float4*)(W_hh + (long)src * HH + (kc - EE - DD));
  bf16 o[4] = {f2b(v.x), f2b(v.y), f2b(v.z), f2b(v.w)};
  *(ushort4*)(Wcat + (long)n * XW + kc) = *(const ushort4*)o;
}

// combined bias (reordered) + split-K completion counters zero
__global__ void biasc_kernel(const float* __restrict__ b_ih, const float* __restrict__ b_hh,
                             float* __restrict__ bc, int* __restrict__ cnt) {
  int i = blockIdx.x * blockDim.x + threadIdx.x;
  if (i < 4 * HH) {
    int src = (i & 3) * HH + (i >> 2);
    bc[i] = b_ih[src] + b_hh[src];
  }
  if (i < TT * 32) cnt[i] = 0;
}

// Ua [H][H] fp32 -> UaT [k][ch] bf16 (64x64 LDS tile transpose)
__global__ void transpose_ua(const float* __restrict__ Ua, bf16* __restrict__ UaT) {
  __shared__ float tile[64][65];
  int tx = threadIdx.x & 63, ty = threadIdx.x >> 6;
  int c0 = blockIdx.x * 64, k0 = blockIdx.y * 64;
  for (int r = ty; r < 64; r += 4)
    tile[r][tx] = Ua[(long)(c0 + r) * HH + k0 + tx];
  __syncthreads();
  for (int r = ty; r < 64; r += 4)
    UaT[(long)(k0 + r) * HH + c0 + tx] = f2b(tile[tx][r]);
}

// embedding gather for ALL steps -> xcat_all[t][:,0:E] bf16
__global__ void embed_all_kernel(const int* __restrict__ cap, const float* __restrict__ emb,
                                 bf16* __restrict__ xcat_all) {
  long idx = (long)blockIdx.x * blockDim.x + threadIdx.x;
  int bt = (int)(idx >> 7);
  int e4 = ((int)idx & 127) * 4;
  int b = bt / TT, t = bt - b * TT;
  int tok = cap[b * TT + t];
  float4 v = *(const float4*)(emb + (long)tok * EE + e4);
  bf16 o[4] = {f2b(v.x), f2b(v.y), f2b(v.z), f2b(v.w)};
  *(ushort4*)(xcat_all + ((long)t * BQ + b) * XW + e4) = *(const ushort4*)o;
}

// ================= K2: attn(t) [blocks 0..127] || fc1+BN2(t-1) [blocks 128..159]
__global__ __launch_bounds__(512) void step_attn_fc(
    const bf16* __restrict__ att1, const bf16* __restrict__ hbf,
    const bf16* __restrict__ UaT, const float* __restrict__ bu,
    const float* __restrict__ va, const float* __restrict__ bv,
    const bf16* __restrict__ feat, bf16* __restrict__ xcat,
    float* __restrict__ att_out, int t, int do_attn,
    const bf16* __restrict__ fcw, const float* __restrict__ fcb,
    const float* __restrict__ g2, const float* __restrict__ be2,
    bf16* __restrict__ out2, int do_fc) {
  __shared__ __align__(16) char smem[29824];
  int blk = blockIdx.x, tid = threadIdx.x;
  if (blk < 128) {
    // ---------- attention segment ----------
    if (!do_attn) return;
    int b = blk;
    float* hs = (float*)smem;        // 512
    float* vas = hs + 512;           // 512
    float* a2s = vas + 512;          // 512
    float* a2p = a2s + 512;          // 1024
    float* sc = a2p + 1024;          // 64
    hs[tid] = b2f(hbf[b * HH + tid]);
    vas[tid] = va[tid];
    __syncthreads();
    // a2 = h @ Ua^T + bu, split over k-halves: tid<256 -> k[0,256), else k[256,512)
    {
      int half = tid >> 8, cp = (tid & 255) * 2;
      const bf16* up = UaT + (long)(half * 256) * HH + cp;
      const float* hh = hs + half * 256;
      float a0 = 0.f, a1 = 0.f;
#pragma unroll 8
      for (int k = 0; k < 256; ++k) {
        uint u = *(const uint*)(up + (long)k * HH);
        float hk = hh[k];
        a0 += hk * b2f(((const bf16*)&u)[0]);
        a1 += hk * b2f(((const bf16*)&u)[1]);
      }
      a2p[half * 512 + cp] = a0;
      a2p[half * 512 + cp + 1] = a1;
    }
    __syncthreads();
    if (tid < 256) {
      int ch = tid * 2;
      a2s[ch] = a2p[ch] + a2p[512 + ch] + bu[ch];
      a2s[ch + 1] = a2p[ch + 1] + a2p[512 + ch + 1] + bu[ch + 1];
    }
    __syncthreads();
    int wave = tid >> 6, lane = tid & 63;
    // hoist per-lane va / a2 slices to registers (reused across score rows)
    float vreg[8], areg[8];
    *(float4*)&vreg[0] = *(const float4*)&vas[lane * 8];
    *(float4*)&vreg[4] = *(const float4*)&vas[lane * 8 + 4];
    *(float4*)&areg[0] = *(const float4*)&a2s[lane * 8];
    *(float4*)&areg[4] = *(const float4*)&a2s[lane * 8 + 4];
    for (int r = wave; r < RR; r += 8) {
      bf16 rv[8];
      *(uint4*)rv = *(const uint4*)(att1 + ((long)b * RR + r) * HH + lane * 8);
      float p = 0.f;
#pragma unroll
      for (int j = 0; j < 8; ++j)
        p += vreg[j] * tanh_fast(b2f(rv[j]) + areg[j]);
#pragma unroll
      for (int off = 32; off > 0; off >>= 1) p += __shfl_down(p, off, 64);
      if (lane == 0) sc[r] = p + bv[0];
    }
    __syncthreads();
    if (tid < 64) {
      float v = (tid < RR) ? sc[tid] : -1e30f;
      float m = v;
#pragma unroll
      for (int off = 32; off > 0; off >>= 1) m = fmaxf(m, __shfl_xor(m, off, 64));
      float e = (tid < RR) ? __expf(v - m) : 0.f;
      float s = e;
#pragma unroll
      for (int off = 32; off > 0; off >>= 1) s += __shfl_xor(s, off, 64);
      float wgt = e / s;
      if (tid < RR) {
        sc[tid] = wgt;
        att_out[((long)b * TT + t) * RR + tid] = wgt;
      }
    }
    __syncthreads();
    // ctx: 512 threads x 4 d's
    const bf16* fb = feat + (long)b * RR * DD + tid * 4;
    float ac[4] = {};
    for (int r = 0; r < RR; ++r) {
      uint2 u = *(const uint2*)(fb + (long)r * DD);
      const bf16* pv = (const bf16*)&u;
      float wr = sc[r];
#pragma unroll
      for (int j = 0; j < 4; ++j) ac[j] += wr * b2f(pv[j]);
    }
    bf16 ov[4];
#pragma unroll
    for (int j = 0; j < 4; ++j) ov[j] = f2b(ac[j]);
    *(uint2*)(xcat + (long)b * XW + EE + tid * 4) = *(const uint2*)ov;
  } else {
    // ---------- fc1 + ReLU + BN2 segment ----------
    if (!do_fc) return;
    int ch0 = (blk - 128) * 8;
    short* wlds = (short*)smem;              // 8*512 = 4096 shorts
    short* hlds = wlds + 4096;               // 128 rows x 68 pitch = 8704 shorts
    float* red = (float*)(smem + (4096 + 8704) * 2);  // [8][130]
    float* stat = red + 8 * 130;
    const int HP = 68;  // 136B pitch -> only 2-way bank alias
    *(bf16x8*)&wlds[tid * 8] = *(const bf16x8*)(fcw + (long)ch0 * HH + tid * 8);
    int b = tid & 127, cg = tid >> 7;  // cg in 0..3, 2 channels each
    float acc2[2] = {0.f, 0.f};
    // staging: each thread writes rows srow and srow+64 -> all 128 rows
    int srow = tid >> 3, sc8 = (tid & 7) * 8;
    for (int k0 = 0; k0 < HH; k0 += 64) {
      __syncthreads();
      *(uint4*)&hlds[srow * HP + sc8] =
          *(const uint4*)(hbf + (long)srow * HH + k0 + sc8);
      *(uint4*)&hlds[(srow + 64) * HP + sc8] =
          *(const uint4*)(hbf + (long)(srow + 64) * HH + k0 + sc8);
      __syncthreads();
#pragma unroll
      for (int kk = 0; kk < 64; kk += 8) {
        bf16 hv[8];
        *(uint4*)hv = *(const uint4*)&hlds[b * HP + kk];
        float hf[8];
#pragma unroll
        for (int j = 0; j < 8; ++j) hf[j] = b2f(hv[j]);
#pragma unroll
        for (int jc = 0; jc < 2; ++jc) {
          const bf16* wr = (const bf16*)&wlds[(cg * 2 + jc) * 512 + k0 + kk];
#pragma unroll
          for (int j = 0; j < 8; ++j) acc2[jc] += hf[j] * b2f(wr[j]);
        }
      }
    }
    float val2[2], dv2[2];
#pragma unroll
    for (int jc = 0; jc < 2; ++jc) {
      int cl = cg * 2 + jc;
      val2[jc] = fmaxf(acc2[jc] + fcb[ch0 + cl], 0.f);
      red[cl * 130 + b] = val2[jc];
    }
    __syncthreads();
    if (tid < 8) {
      float s = 0.f;
      for (int i = 0; i < 128; i += 4)
        s += red[tid * 130 + i] + red[tid * 130 + i + 1] +
             red[tid * 130 + i + 2] + red[tid * 130 + i + 3];
      stat[tid] = s * (1.f / 128);
    }
    __syncthreads();
#pragma unroll
    for (int jc = 0; jc < 2; ++jc) {
      int cl = cg * 2 + jc;
      dv2[jc] = val2[jc] - stat[cl];
      red[cl * 130 + b] = dv2[jc] * dv2[jc];
    }
    __syncthreads();
    if (tid < 8) {
      float s = 0.f;
      for (int i = 0; i < 128; i += 4)
        s += red[tid * 130 + i] + red[tid * 130 + i + 1] +
             red[tid * 130 + i + 2] + red[tid * 130 + i + 3];
      stat[tid] = 1.f / sqrtf(s * (1.f / 128) + EPSV);
    }
    __syncthreads();
#pragma unroll
    for (int jc = 0; jc < 2; ++jc) {
      int cl = cg * 2 + jc;
      out2[(long)b * 256 + ch0 + cl] =
          f2b(dv2[jc] * stat[cl] * g2[ch0 + cl] + be2[ch0 + cl]);
    }
  }
}

// ================= K3: gates GEMM split-K x4 + fused LSTM/BN1 [blocks 0..127]
//                      || fc2 [blocks 128..284]
// Wcat rows are reordered (4*ch+gate) so tile bn holds all 4 gates of
// hidden channels [bn/4, bn/4+16). Last kz block per tile (via device-scope
// atomic counter) sums partials and runs LSTM pointwise + BN1.
__global__ __launch_bounds__(256) void step_gemms(
    const bf16* __restrict__ xc, const bf16* __restrict__ Wcat,
    const float* __restrict__ biasc, float* __restrict__ gatesT,
    const bf16* __restrict__ out2, const bf16* __restrict__ fc2w,
    const float* __restrict__ fc2b, float* __restrict__ outp,
    int* __restrict__ cnt, float* __restrict__ cT,
    bf16* __restrict__ hbf, bf16* __restrict__ xnext,
    const float* __restrict__ g1, const float* __restrict__ be1,
    int t, int do_gates, int do_fc2) {
  __shared__ __align__(16) short Alds[128 * APITCH];
  __shared__ __align__(16) short Wlds[64 * APITCH];
  __shared__ int lastflag;
  int blk = blockIdx.x, tid = threadIdx.x;
  int w = tid >> 6, l = tid & 63;
  int lr = l & 15, lq = l >> 4;
  int srow = tid >> 2, skq = (tid & 3) * 8;
  if (blk < 128) {
    if (!do_gates) return;
    const int KC = XW / 4;  // 768
    int tile = blk & 31, kz = blk >> 5;
    int bn = tile * 64, kbeg = kz * KC;
    const bf16* pa0 = xc + (long)srow * XW + kbeg + skq;
    const bf16* pa1 = pa0 + (long)64 * XW;
    const bf16* pw = Wcat + (long)(bn + srow) * XW + kbeg + skq;
    f32x4 acc[2][4] = {};
    uint4 ra0 = *(const uint4*)pa0;
    uint4 ra1 = *(const uint4*)pa1;
    uint4 rw = *(const uint4*)pw;
    for (int k0 = 0; k0 < KC; k0 += 32) {
      __syncthreads();
      *(uint4*)&Alds[srow * APITCH + skq] = ra0;
      *(uint4*)&Alds[(srow + 64) * APITCH + skq] = ra1;
      *(uint4*)&Wlds[srow * APITCH + skq] = rw;
      if (k0 + 32 < KC) {
        ra0 = *(const uint4*)(pa0 + k0 + 32);
        ra1 = *(const uint4*)(pa1 + k0 + 32);
        rw = *(const uint4*)(pw + k0 + 32);
      }
      __syncthreads();
      bf16x8 af[2], bfr[4];
#pragma unroll
      for (int mt = 0; mt < 2; ++mt)
        af[mt] = *(const bf16x8*)&Alds[(w * 32 + mt * 16 + lr) * APITCH + lq * 8];
#pragma unroll
      for (int nt = 0; nt < 4; ++nt)
        bfr[nt] = *(const bf16x8*)&Wlds[(nt * 16 + lr) * APITCH + lq * 8];
#pragma unroll
      for (int mt = 0; mt < 2; ++mt)
#pragma unroll
        for (int nt = 0; nt < 4; ++nt)
          acc[mt][nt] = __builtin_amdgcn_mfma_f32_16x16x32_bf16(
              af[mt], bfr[nt], acc[mt][nt], 0, 0, 0);
    }
    // transposed partial: gatesT[kz][gn][b]  (gn in reordered gate space)
    const long GP = (long)4 * HH * 128;
    float* Cf = gatesT + (long)kz * GP;
#pragma unroll
    for (int mt = 0; mt < 2; ++mt) {
      int gm = w * 32 + mt * 16 + lq * 4;
#pragma unroll
      for (int nt = 0; nt < 4; ++nt) {
        int gn = bn + nt * 16 + lr;
        float bv = (kz == 0) ? biasc[gn] : 0.f;
#pragma unroll
        for (int i = 0; i < 4; ++i)
          Cf[(long)gn * 128 + gm + i] = acc[mt][nt][i] + bv;
      }
    }
    // ---- split-K completion: last block per tile runs LSTM + BN1 ----
    __threadfence();
    __syncthreads();
    if (tid == 0) lastflag = (atomicAdd(&cnt[t * 32 + tile], 1) == 3);
    __syncthreads();
    if (!lastflag) return;
    __threadfence();  // acquire: see other blocks' partials
    // 256 threads: ch_l = tid>>4 (16 channels), b0 = (tid&15)*8 (8 batches)
    int ch_l = tid >> 4, b0 = (tid & 15) * 8;
    int ch = (bn >> 2) + ch_l;
    float gv[4][8];
#pragma unroll
    for (int g = 0; g < 4; ++g) {
      int gn = bn + ch_l * 4 + g;
      const float* s0 = gatesT + (long)gn * 128 + b0;
      float4 x0 = *(const float4*)s0;
      float4 x1 = *(const float4*)(s0 + 4);
#pragma unroll
      for (int z = 1; z < 4; ++z) {
        const float* sz = s0 + z * GP;
        float4 y0 = *(const float4*)sz;
        float4 y1 = *(const float4*)(sz + 4);
        x0.x += y0.x; x0.y += y0.y; x0.z += y0.z; x0.w += y0.w;
        x1.x += y1.x; x1.y += y1.y; x1.z += y1.z; x1.w += y1.w;
      }
      gv[g][0] = x0.x; gv[g][1] = x0.y; gv[g][2] = x0.z; gv[g][3] = x0.w;
      gv[g][4] = x1.x; gv[g][5] = x1.y; gv[g][6] = x1.z; gv[g][7] = x1.w;
    }
    float* cp = cT + (long)ch * 128 + b0;
    float4 c0v = *(const float4*)cp;
    float4 c1v = *(const float4*)(cp + 4);
    float cold[8] = {c0v.x, c0v.y, c0v.z, c0v.w, c1v.x, c1v.y, c1v.z, c1v.w};
    float hr[8];
#pragma unroll
    for (int i = 0; i < 8; ++i) {
      float ig = sigmoidf(gv[0][i]);
      float fg = sigmoidf(gv[1][i]);
      float gg = tanh_fast(gv[2][i]);
      float og = sigmoidf(gv[3][i]);
      float cn = fg * cold[i] + ig * gg;
      cold[i] = cn;
      hr[i] = og * tanh_fast(cn);
    }
    *(float4*)cp = make_float4(cold[0], cold[1], cold[2], cold[3]);
    *(float4*)(cp + 4) = make_float4(cold[4], cold[5], cold[6], cold[7]);
    // BN1 over batch (128) per channel: reduce across 16 threads per ch_l
    float* red = (float*)Alds;  // [16][17]
    int bgrp = tid & 15;
    float s = 0.f;
#pragma unroll
    for (int i = 0; i < 8; ++i) s += hr[i];
    red[ch_l * 17 + bgrp] = s;
    __syncthreads();
    __shared__ float mstat[16], vstat[16];
    if (tid < 16) {
      float m = 0.f;
      for (int j = 0; j < 16; ++j) m += red[tid * 17 + j];
      mstat[tid] = m * (1.f / 128);
    }
    __syncthreads();
    float mean = mstat[ch_l];
    float dv[8];
    float sv = 0.f;
#pragma unroll
    for (int i = 0; i < 8; ++i) { dv[i] = hr[i] - mean; sv += dv[i] * dv[i]; }
    red[ch_l * 17 + bgrp] = sv;
    __syncthreads();
    if (tid < 16) {
      float m = 0.f;
      for (int j = 0; j < 16; ++j) m += red[tid * 17 + j];
      vstat[tid] = 1.f / sqrtf(m * (1.f / 128) + EPSV);
    }
    __syncthreads();
    float rstd = vstat[ch_l], gg1 = g1[ch], bb1 = be1[ch];
#pragma unroll
    for (int i = 0; i < 8; ++i) {
      bf16 res = f2b(dv[i] * rstd * gg1 + bb1);
      hbf[(long)(b0 + i) * HH + ch] = res;
      xnext[(long)(b0 + i) * XW + EE + DD + ch] = res;
    }
  } else {
    if (!do_fc2) return;
    int bn = (blk - 128) * 64;
    const bf16* pa0 = out2 + (long)srow * 256 + skq;
    const bf16* pa1 = pa0 + (long)64 * 256;
    const bf16* pw = fc2w + (long)(bn + srow) * 256 + skq;
    bool wok = (bn + srow) < VV;
    f32x4 acc[2][4] = {};
    uint4 ra0 = *(const uint4*)pa0;
    uint4 ra1 = *(const uint4*)pa1;
    uint4 rw = wok ? *(const uint4*)pw : make_uint4(0, 0, 0, 0);
    for (int k0 = 0; k0 < 256; k0 += 32) {
      __syncthreads();
      *(uint4*)&Alds[srow * APITCH + skq] = ra0;
      *(uint4*)&Alds[(srow + 64) * APITCH + skq] = ra1;
      *(uint4*)&Wlds[srow * APITCH + skq] = rw;
      if (k0 + 32 < 256) {
        ra0 = *(const uint4*)(pa0 + k0 + 32);
        ra1 = *(const uint4*)(pa1 + k0 + 32);
        rw = wok ? *(const uint4*)(pw + k0 + 32) : make_uint4(0, 0, 0, 0);
      }
      __syncthreads();
      bf16x8 af[2], bfr[4];
#pragma unroll
      for (int mt = 0; mt < 2; ++mt)
        af[mt] = *(const bf16x8*)&Alds[(w * 32 + mt * 16 + lr) * APITCH + lq * 8];
#pragma unroll
      for (int nt = 0; nt < 4; ++nt)
        bfr[nt] = *(const bf16x8*)&Wlds[(nt * 16 + lr) * APITCH + lq * 8];
#pragma unroll
      for (int mt = 0; mt < 2; ++mt)
#pragma unroll
        for (int nt = 0; nt < 4; ++nt)
          acc[mt][nt] = __builtin_amdgcn_mfma_f32_16x16x32_bf16(
              af[mt], bfr[nt], acc[mt][nt], 0, 0, 0);
    }
    const long ldc = (long)TT * VV;
#pragma unroll
    for (int mt = 0; mt < 2; ++mt) {
      int gm = w * 32 + mt * 16 + lq * 4;
#pragma unroll
      for (int nt = 0; nt < 4; ++nt) {
        int gn = bn + nt * 16 + lr;
        if (gn >= VV) continue;
        float bv = fc2b[gn];
#pragma unroll
        for (int i = 0; i < 4; ++i)
          outp[(long)(gm + i) * ldc + gn] = acc[mt][nt][i] + bv;
      }
    }
  }
}

extern "C" void kernel_launch(void* const* d_in, const int* in_sizes, int n_in,
                              void* d_out, int out_size, void* d_ws, size_t ws_size,
                              hipStream_t stream) {
  const int* captions  = (const int*)d_in[0];
  const float* features = (const float*)d_in[1];
  const float* emb   = (const float*)d_in[2];
  const float* Wa    = (const float*)d_in[3];
  const float* ba    = (const float*)d_in[4];
  const float* Ua    = (const float*)d_in[5];
  const float* bu    = (const float*)d_in[6];
  const float* va    = (const float*)d_in[7];
  const float* bv    = (const float*)d_in[8];
  const float* W_ih  = (const float*)d_in[9];
  const float* b_ih  = (const float*)d_in[10];
  const float* W_hh  = (const float*)d_in[11];
  const float* b_hh  = (const float*)d_in[12];
  const float* g1    = (const float*)d_in[13];
  const float* be1   = (const float*)d_in[14];
  const float* fc_w  = (const float*)d_in[15];
  const float* fc_b  = (const float*)d_in[16];
  const float* g2    = (const float*)d_in[17];
  const float* be2   = (const float*)d_in[18];
  const float* fc2_w = (const float*)d_in[19];
  const float* fc2_b = (const float*)d_in[20];
  const float* ih_w  = (const float*)d_in[21];
  const float* ih_b  = (const float*)d_in[22];
  const float* ic_w  = (const float*)d_in[23];
  const float* ic_b  = (const float*)d_in[24];

  float* out = (float*)d_out;                 // [B,T,V]
  float* att_out = out + (long)BQ * TT * VV;  // [B,T,R]

  char* p = (char*)d_ws;
  auto alloc = [&](size_t bytes) { char* r = p; p += (bytes + 255) & ~255ULL; return r; };
  bf16* featbf = (bf16*)alloc((size_t)BQ * RR * DD * 2);
  bf16* meanbf = (bf16*)alloc((size_t)BQ * DD * 2);
  bf16* Wcat   = (bf16*)alloc((size_t)4 * HH * XW * 2);
  bf16* Wabf   = (bf16*)alloc((size_t)HH * DD * 2);
  bf16* UaTbf  = (bf16*)alloc((size_t)HH * HH * 2);
  bf16* fcwbf  = (bf16*)alloc((size_t)256 * HH * 2);
  bf16* fc2wbf = (bf16*)alloc((size_t)VV * 256 * 2);
  bf16* ihwbf  = (bf16*)alloc((size_t)HH * DD * 2);
  bf16* icwbf  = (bf16*)alloc((size_t)HH * DD * 2);
  bf16* att1bf = (bf16*)alloc((size_t)BQ * RR * HH * 2);
  bf16* xcat_all = (bf16*)alloc((size_t)(TT + 1) * BQ * XW * 2);
  bf16* hbf    = (bf16*)alloc((size_t)BQ * HH * 2);
  bf16* out2bf = (bf16*)alloc((size_t)BQ * 256 * 2);
  float* biasc = (float*)alloc((size_t)4 * HH * 4);
  float* cT    = (float*)alloc((size_t)BQ * HH * 4);
  float* gatesT = (float*)alloc((size_t)4 * BQ * 4 * HH * 4);  // 4 split-K partials, [gn][b]
  int* cnt     = (int*)alloc((size_t)TT * 32 * 4);

  // ---- prologue ----
  f2b_kernel<<<(BQ * RR * DD / 4 + 255) / 256, 256, 0, stream>>>(features, featbf, BQ * RR * DD / 4);
  f2b_kernel<<<(HH * DD / 4 + 255) / 256, 256, 0, stream>>>(Wa, Wabf, HH * DD / 4);
  transpose_ua<<<dim3(8, 8), 256, 0, stream>>>(Ua, UaTbf);
  f2b_kernel<<<(256 * HH / 4 + 255) / 256, 256, 0, stream>>>(fc_w, fcwbf, 256 * HH / 4);
  f2b_kernel<<<(VV * 256 / 4 + 255) / 256, 256, 0, stream>>>(fc2_w, fc2wbf, VV * 256 / 4);
  f2b_kernel<<<(HH * DD / 4 + 255) / 256, 256, 0, stream>>>(ih_w, ihwbf, HH * DD / 4);
  f2b_kernel<<<(HH * DD / 4 + 255) / 256, 256, 0, stream>>>(ic_w, icwbf, HH * DD / 4);
  wcat_kernel<<<dim3(XW / 4 / 256, 4 * HH), 256, 0, stream>>>(W_ih, W_hh, Wcat);
  biasc_kernel<<<(4 * HH + 255) / 256, 256, 0, stream>>>(b_ih, b_hh, biasc, cnt);
  mean_kernel<<<(BQ * DD + 255) / 256, 256, 0, stream>>>(featbf, meanbf);
  embed_all_kernel<<<(BQ * TT * EE / 4) / 256, 256, 0, stream>>>(captions, emb, xcat_all);

  // h0 -> hbf + xcat_0 h-slice; c0 -> cT (fp32, transposed [ch][b])
  gemm_mfma<<<dim3(HH / 64, 1), 256, 0, stream>>>(
      meanbf, ihwbf, ih_b, nullptr, hbf, xcat_all + EE + DD, HH, XW, HH, DD, 0, 0);
  gemm_mfma<<<dim3(HH / 64, 1), 256, 0, stream>>>(
      meanbf, icwbf, ic_b, cT, nullptr, nullptr, 128, 0, HH, DD, 0, 1);
  // att1 = features @ Wa^T + ba  (bf16 out)
  gemm_mfma<<<dim3(HH / 64, BQ * RR / 128), 256, 0, stream>>>(
      featbf, Wabf, ba, nullptr, att1bf, nullptr, HH, 0, HH, DD, 0, 0);

  // ---- timestep loop: 2 kernels/step ----
  for (int t = 0; t < TT; ++t) {
    bf16* xc = xcat_all + (size_t)t * BQ * XW;
    bf16* xn = xcat_all + (size_t)(t + 1) * BQ * XW;
    // attn(t) || fc1+bn2 on h(t-1)
    step_attn_fc<<<160, 512, 0, stream>>>(
        att1bf, hbf, UaTbf, bu, va, bv, featbf, xc, att_out, t, 1,
        fcwbf, fc_b, g2, be2, out2bf, t > 0 ? 1 : 0);
    // gates(t)+lstm(t) || fc2(t-1)
    step_gemms<<<285, 256, 0, stream>>>(
        xc, Wcat, biasc, gatesT, out2bf, fc2wbf, fc2_b,
        out + (long)(t > 0 ? t - 1 : 0) * VV,
        cnt, cT, hbf, xn, g1, be1, t, 1, t > 0 ? 1 : 0);
  }
  // tail: fc1+bn2 and fc2 for t = TT-1
  step_attn_fc<<<160, 512, 0, stream>>>(
      att1bf, hbf, UaTbf, bu, va, bv, featbf, xcat_all, att_out, 0, 0,
      fcwbf, fc_b, g2, be2, out2bf, 1);
  step_gemms<<<285, 256, 0, stream>>>(
      xcat_all, Wcat, biasc, gatesT, out2bf, fc2wbf, fc2_b,
      out + (long)(TT - 1) * VV,
      cnt, cT, hbf, xcat_all, g1, be1, 0, 0, 1);
}

// Round 5
// 1436.692 us; speedup vs baseline: 1.2597x; 1.2597x over previous
//
#include <hip/hip_runtime.h>
#include <hip/hip_bf16.h>
#include <math.h>

typedef __hip_bfloat16 bf16;
typedef short bf16x8 __attribute__((ext_vector_type(8)));
typedef float f32x4 __attribute__((ext_vector_type(4)));

#define BQ 128   // batch
#define TT 20    // timesteps
#define RR 49    // regions
#define DD 2048  // feature dim
#define EE 512   // embed dim
#define HH 512   // hidden
#define VV 10000 // vocab
#define XW 3072  // xcat width = E + D + H
constexpr float EPSV = 1e-5f;
#define APITCH 40  // LDS row pitch in bf16 elems (80B) — breaks pow2 bank stride
#define KZ 8       // gates split-K depth (256 gates blocks -> ~2 blocks/CU TLP)

__device__ __forceinline__ float sigmoidf(float x) { return 1.f / (1.f + __expf(-x)); }
__device__ __forceinline__ float tanh_fast(float x) {
  float e = __expf(2.f * x);
  return 1.f - 2.f / (e + 1.f);
}
__device__ __forceinline__ bf16 f2b(float v) { return __float2bfloat16(v); }
__device__ __forceinline__ float b2f(bf16 v) { return __bfloat162float(v); }

// ---------------- MFMA GEMM (prologue only) ----------------
// C[M,N] = A[M,K] @ W[N,K]^T + bias. A,W bf16 K-contiguous.
// transC: store Cf[gn*ldc + row] instead of Cf[row*ldc + gn].
__global__ __launch_bounds__(256) void gemm_mfma(
    const bf16* __restrict__ A, const bf16* __restrict__ W,
    const float* __restrict__ bias,
    float* __restrict__ Cf, bf16* __restrict__ Cb, bf16* __restrict__ Cb2,
    long ldc, long ldc2, int N, int K, int act, int transC) {
  __shared__ __align__(16) short Alds[128 * APITCH];
  __shared__ __align__(16) short Wlds[64 * APITCH];
  int tid = threadIdx.x;
  int bm = blockIdx.y * 128, bn = blockIdx.x * 64;
  int w = tid >> 6, l = tid & 63;
  int lr = l & 15, lq = l >> 4;              // C col / k-quad
  int srow = tid >> 2, skq = (tid & 3) * 8;  // staging row / k-offset
  const bf16* pa0 = A + (long)(bm + srow) * K + skq;
  const bf16* pa1 = pa0 + (long)64 * K;
  const bf16* pw = W + (long)(bn + srow) * K + skq;
  bool wok = (bn + srow) < N;
  f32x4 acc[2][4] = {};
  uint4 ra0 = *(const uint4*)pa0;
  uint4 ra1 = *(const uint4*)pa1;
  uint4 rw = wok ? *(const uint4*)pw : make_uint4(0, 0, 0, 0);
  for (int k0 = 0; k0 < K; k0 += 32) {
    __syncthreads();
    *(uint4*)&Alds[srow * APITCH + skq] = ra0;
    *(uint4*)&Alds[(srow + 64) * APITCH + skq] = ra1;
    *(uint4*)&Wlds[srow * APITCH + skq] = rw;
    if (k0 + 32 < K) {
      ra0 = *(const uint4*)(pa0 + k0 + 32);
      ra1 = *(const uint4*)(pa1 + k0 + 32);
      rw = wok ? *(const uint4*)(pw + k0 + 32) : make_uint4(0, 0, 0, 0);
    }
    __syncthreads();
    bf16x8 af[2], bfr[4];
#pragma unroll
    for (int mt = 0; mt < 2; ++mt)
      af[mt] = *(const bf16x8*)&Alds[(w * 32 + mt * 16 + lr) * APITCH + lq * 8];
#pragma unroll
    for (int nt = 0; nt < 4; ++nt)
      bfr[nt] = *(const bf16x8*)&Wlds[(nt * 16 + lr) * APITCH + lq * 8];
#pragma unroll
    for (int mt = 0; mt < 2; ++mt)
#pragma unroll
      for (int nt = 0; nt < 4; ++nt)
        acc[mt][nt] = __builtin_amdgcn_mfma_f32_16x16x32_bf16(
            af[mt], bfr[nt], acc[mt][nt], 0, 0, 0);
  }
#pragma unroll
  for (int mt = 0; mt < 2; ++mt) {
    int gm = bm + w * 32 + mt * 16 + lq * 4;
#pragma unroll
    for (int nt = 0; nt < 4; ++nt) {
      int gn = bn + nt * 16 + lr;
      if (gn >= N) continue;
      float bv = bias ? bias[gn] : 0.f;
#pragma unroll
      for (int i = 0; i < 4; ++i) {
        float v = acc[mt][nt][i] + bv;
        if (act) v = fmaxf(v, 0.f);
        long row = gm + i;
        if (Cf) {
          if (transC) Cf[(long)gn * ldc + row] = v;
          else Cf[row * ldc + gn] = v;
        }
        if (Cb) Cb[row * ldc + gn] = f2b(v);
        if (Cb2) Cb2[row * ldc2 + gn] = f2b(v);
      }
    }
  }
}

// ---------------- small kernels ----------------
// mean over R regions (bf16 in) -> bf16 [B,D]
__global__ void mean_kernel(const bf16* __restrict__ feat, bf16* __restrict__ meanbf) {
  int idx = blockIdx.x * blockDim.x + threadIdx.x;
  if (idx >= BQ * DD) return;
  int b = idx / DD, d = idx - b * DD;
  const bf16* p = feat + (long)b * RR * DD + d;
  float s = 0.f;
  for (int r = 0; r < RR; ++r) s += b2f(p[(long)r * DD]);
  meanbf[idx] = f2b(s * (1.f / RR));
}

// fp32 -> bf16, 4 elems/thread
__global__ void f2b_kernel(const float* __restrict__ src, bf16* __restrict__ dst, long n4) {
  long i = (long)blockIdx.x * blockDim.x + threadIdx.x;
  if (i >= n4) return;
  float4 v = ((const float4*)src)[i];
  bf16 o[4] = {f2b(v.x), f2b(v.y), f2b(v.z), f2b(v.w)};
  *(ushort4*)(dst + i * 4) = *(const ushort4*)o;
}

// pack [W_ih | W_hh] -> Wcat bf16 [2048][3072]
__global__ void wcat_kernel(const float* __restrict__ W_ih, const float* __restrict__ W_hh,
                            bf16* __restrict__ Wcat) {
  int n = blockIdx.y;
  int kc = (blockIdx.x * blockDim.x + threadIdx.x) * 4;
  float4 v = (kc < EE + DD) ? *(const float4*)(W_ih + (long)n * (EE + DD) + kc)
                            : *(const float4*)(W_hh + (long)n * HH + (kc - EE - DD));
  bf16 o[4] = {f2b(v.x), f2b(v.y), f2b(v.z), f2b(v.w)};
  *(ushort4*)(Wcat + (long)n * XW + kc) = *(const ushort4*)o;
}

__global__ void biasc_kernel(const float* __restrict__ b_ih, const float* __restrict__ b_hh,
                             float* __restrict__ bc) {
  int i = blockIdx.x * blockDim.x + threadIdx.x;
  if (i < 4 * HH) bc[i] = b_ih[i] + b_hh[i];
}

// Ua [H][H] fp32 -> UaT [k][ch] bf16 (64x64 LDS tile transpose)
__global__ void transpose_ua(const float* __restrict__ Ua, bf16* __restrict__ UaT) {
  __shared__ float tile[64][65];
  int tx = threadIdx.x & 63, ty = threadIdx.x >> 6;
  int c0 = blockIdx.x * 64, k0 = blockIdx.y * 64;
  for (int r = ty; r < 64; r += 4)
    tile[r][tx] = Ua[(long)(c0 + r) * HH + k0 + tx];
  __syncthreads();
  for (int r = ty; r < 64; r += 4)
    UaT[(long)(k0 + r) * HH + c0 + tx] = f2b(tile[tx][r]);
}

// embedding gather for ALL steps -> xcat_all[t][:,0:E] bf16
__global__ void embed_all_kernel(const int* __restrict__ cap, const float* __restrict__ emb,
                                 bf16* __restrict__ xcat_all) {
  long idx = (long)blockIdx.x * blockDim.x + threadIdx.x;
  int bt = (int)(idx >> 7);
  int e4 = ((int)idx & 127) * 4;
  int b = bt / TT, t = bt - b * TT;
  int tok = cap[b * TT + t];
  float4 v = *(const float4*)(emb + (long)tok * EE + e4);
  bf16 o[4] = {f2b(v.x), f2b(v.y), f2b(v.z), f2b(v.w)};
  *(ushort4*)(xcat_all + ((long)t * BQ + b) * XW + e4) = *(const ushort4*)o;
}

// ================= K2: attn(t) [blocks 0..127] || fc1+BN2(t-1) [blocks 128..159]
__global__ __launch_bounds__(512) void step_attn_fc(
    const bf16* __restrict__ att1, const bf16* __restrict__ hbf,
    const bf16* __restrict__ UaT, const float* __restrict__ bu,
    const float* __restrict__ va, const float* __restrict__ bv,
    const bf16* __restrict__ feat, bf16* __restrict__ xcat,
    float* __restrict__ att_out, int t, int do_attn,
    const bf16* __restrict__ fcw, const float* __restrict__ fcb,
    const float* __restrict__ g2, const float* __restrict__ be2,
    bf16* __restrict__ out2, int do_fc) {
  __shared__ __align__(16) char smem[29824];
  int blk = blockIdx.x, tid = threadIdx.x;
  if (blk < 128) {
    // ---------- attention segment ----------
    if (!do_attn) return;
    int b = blk;
    float* hs = (float*)smem;        // 512
    float* vas = hs + 512;           // 512
    float* a2s = vas + 512;          // 512
    float* a2p = a2s + 512;          // 1024
    float* sc = a2p + 1024;          // 64
    hs[tid] = b2f(hbf[b * HH + tid]);
    vas[tid] = va[tid];
    __syncthreads();
    // a2 = h @ Ua^T + bu, split over k-halves: tid<256 -> k[0,256), else k[256,512)
    {
      int half = tid >> 8, cp = (tid & 255) * 2;
      const bf16* up = UaT + (long)(half * 256) * HH + cp;
      const float* hh = hs + half * 256;
      float a0 = 0.f, a1 = 0.f;
#pragma unroll 8
      for (int k = 0; k < 256; ++k) {
        uint u = *(const uint*)(up + (long)k * HH);
        float hk = hh[k];
        a0 += hk * b2f(((const bf16*)&u)[0]);
        a1 += hk * b2f(((const bf16*)&u)[1]);
      }
      a2p[half * 512 + cp] = a0;
      a2p[half * 512 + cp + 1] = a1;
    }
    __syncthreads();
    if (tid < 256) {
      int ch = tid * 2;
      a2s[ch] = a2p[ch] + a2p[512 + ch] + bu[ch];
      a2s[ch + 1] = a2p[ch + 1] + a2p[512 + ch + 1] + bu[ch + 1];
    }
    __syncthreads();
    int wave = tid >> 6, lane = tid & 63;
    // hoist per-lane va / a2 slices to registers (reused across score rows)
    float vreg[8], areg[8];
    *(float4*)&vreg[0] = *(const float4*)&vas[lane * 8];
    *(float4*)&vreg[4] = *(const float4*)&vas[lane * 8 + 4];
    *(float4*)&areg[0] = *(const float4*)&a2s[lane * 8];
    *(float4*)&areg[4] = *(const float4*)&a2s[lane * 8 + 4];
    for (int r = wave; r < RR; r += 8) {
      bf16 rv[8];
      *(uint4*)rv = *(const uint4*)(att1 + ((long)b * RR + r) * HH + lane * 8);
      float p = 0.f;
#pragma unroll
      for (int j = 0; j < 8; ++j)
        p += vreg[j] * tanh_fast(b2f(rv[j]) + areg[j]);
#pragma unroll
      for (int off = 32; off > 0; off >>= 1) p += __shfl_down(p, off, 64);
      if (lane == 0) sc[r] = p + bv[0];
    }
    __syncthreads();
    if (tid < 64) {
      float v = (tid < RR) ? sc[tid] : -1e30f;
      float m = v;
#pragma unroll
      for (int off = 32; off > 0; off >>= 1) m = fmaxf(m, __shfl_xor(m, off, 64));
      float e = (tid < RR) ? __expf(v - m) : 0.f;
      float s = e;
#pragma unroll
      for (int off = 32; off > 0; off >>= 1) s += __shfl_xor(s, off, 64);
      float wgt = e / s;
      if (tid < RR) {
        sc[tid] = wgt;
        att_out[((long)b * TT + t) * RR + tid] = wgt;
      }
    }
    __syncthreads();
    // ctx: 512 threads x 4 d's
    const bf16* fb = feat + (long)b * RR * DD + tid * 4;
    float ac[4] = {};
    for (int r = 0; r < RR; ++r) {
      uint2 u = *(const uint2*)(fb + (long)r * DD);
      const bf16* pv = (const bf16*)&u;
      float wr = sc[r];
#pragma unroll
      for (int j = 0; j < 4; ++j) ac[j] += wr * b2f(pv[j]);
    }
    bf16 ov[4];
#pragma unroll
    for (int j = 0; j < 4; ++j) ov[j] = f2b(ac[j]);
    *(uint2*)(xcat + (long)b * XW + EE + tid * 4) = *(const uint2*)ov;
  } else {
    // ---------- fc1 + ReLU + BN2 segment ----------
    if (!do_fc) return;
    int ch0 = (blk - 128) * 8;
    short* wlds = (short*)smem;              // 8*512 = 4096 shorts
    short* hlds = wlds + 4096;               // 128 rows x 68 pitch = 8704 shorts
    float* red = (float*)(smem + (4096 + 8704) * 2);  // [8][130]
    float* stat = red + 8 * 130;
    const int HP = 68;  // 136B pitch -> only 2-way bank alias
    *(bf16x8*)&wlds[tid * 8] = *(const bf16x8*)(fcw + (long)ch0 * HH + tid * 8);
    int b = tid & 127, cg = tid >> 7;  // cg in 0..3, 2 channels each
    float acc2[2] = {0.f, 0.f};
    // staging: each thread writes rows srow and srow+64 -> all 128 rows
    int srow = tid >> 3, sc8 = (tid & 7) * 8;
    for (int k0 = 0; k0 < HH; k0 += 64) {
      __syncthreads();
      *(uint4*)&hlds[srow * HP + sc8] =
          *(const uint4*)(hbf + (long)srow * HH + k0 + sc8);
      *(uint4*)&hlds[(srow + 64) * HP + sc8] =
          *(const uint4*)(hbf + (long)(srow + 64) * HH + k0 + sc8);
      __syncthreads();
#pragma unroll
      for (int kk = 0; kk < 64; kk += 8) {
        bf16 hv[8];
        *(uint4*)hv = *(const uint4*)&hlds[b * HP + kk];
        float hf[8];
#pragma unroll
        for (int j = 0; j < 8; ++j) hf[j] = b2f(hv[j]);
#pragma unroll
        for (int jc = 0; jc < 2; ++jc) {
          const bf16* wr = (const bf16*)&wlds[(cg * 2 + jc) * 512 + k0 + kk];
#pragma unroll
          for (int j = 0; j < 8; ++j) acc2[jc] += hf[j] * b2f(wr[j]);
        }
      }
    }
    float val2[2], dv2[2];
#pragma unroll
    for (int jc = 0; jc < 2; ++jc) {
      int cl = cg * 2 + jc;
      val2[jc] = fmaxf(acc2[jc] + fcb[ch0 + cl], 0.f);
      red[cl * 130 + b] = val2[jc];
    }
    __syncthreads();
    if (tid < 8) {
      float s = 0.f;
      for (int i = 0; i < 128; i += 4)
        s += red[tid * 130 + i] + red[tid * 130 + i + 1] +
             red[tid * 130 + i + 2] + red[tid * 130 + i + 3];
      stat[tid] = s * (1.f / 128);
    }
    __syncthreads();
#pragma unroll
    for (int jc = 0; jc < 2; ++jc) {
      int cl = cg * 2 + jc;
      dv2[jc] = val2[jc] - stat[cl];
      red[cl * 130 + b] = dv2[jc] * dv2[jc];
    }
    __syncthreads();
    if (tid < 8) {
      float s = 0.f;
      for (int i = 0; i < 128; i += 4)
        s += red[tid * 130 + i] + red[tid * 130 + i + 1] +
             red[tid * 130 + i + 2] + red[tid * 130 + i + 3];
      stat[tid] = 1.f / sqrtf(s * (1.f / 128) + EPSV);
    }
    __syncthreads();
#pragma unroll
    for (int jc = 0; jc < 2; ++jc) {
      int cl = cg * 2 + jc;
      out2[(long)b * 256 + ch0 + cl] =
          f2b(dv2[jc] * stat[cl] * g2[ch0 + cl] + be2[ch0 + cl]);
    }
  }
}

// ================= K3: gates GEMM split-K x8 [blocks 0..255] || fc2 [256..412]
__global__ __launch_bounds__(256) void step_gemms(
    const bf16* __restrict__ xc, const bf16* __restrict__ Wcat,
    const float* __restrict__ biasc, float* __restrict__ gatesT,
    const bf16* __restrict__ out2, const bf16* __restrict__ fc2w,
    const float* __restrict__ fc2b, float* __restrict__ outp,
    int do_gates, int do_fc2) {
  __shared__ __align__(16) short Alds[128 * APITCH];
  __shared__ __align__(16) short Wlds[64 * APITCH];
  int blk = blockIdx.x, tid = threadIdx.x;
  int w = tid >> 6, l = tid & 63;
  int lr = l & 15, lq = l >> 4;
  int srow = tid >> 2, skq = (tid & 3) * 8;
  if (blk < 32 * KZ) {
    if (!do_gates) return;
    const int KC = XW / KZ;  // 384
    int tile = blk & 31, kz = blk >> 5;
    int bn = tile * 64, kbeg = kz * KC;
    const bf16* pa0 = xc + (long)srow * XW + kbeg + skq;
    const bf16* pa1 = pa0 + (long)64 * XW;
    const bf16* pw = Wcat + (long)(bn + srow) * XW + kbeg + skq;
    f32x4 acc[2][4] = {};
    uint4 ra0 = *(const uint4*)pa0;
    uint4 ra1 = *(const uint4*)pa1;
    uint4 rw = *(const uint4*)pw;
    for (int k0 = 0; k0 < KC; k0 += 32) {
      __syncthreads();
      *(uint4*)&Alds[srow * APITCH + skq] = ra0;
      *(uint4*)&Alds[(srow + 64) * APITCH + skq] = ra1;
      *(uint4*)&Wlds[srow * APITCH + skq] = rw;
      if (k0 + 32 < KC) {
        ra0 = *(const uint4*)(pa0 + k0 + 32);
        ra1 = *(const uint4*)(pa1 + k0 + 32);
        rw = *(const uint4*)(pw + k0 + 32);
      }
      __syncthreads();
      bf16x8 af[2], bfr[4];
#pragma unroll
      for (int mt = 0; mt < 2; ++mt)
        af[mt] = *(const bf16x8*)&Alds[(w * 32 + mt * 16 + lr) * APITCH + lq * 8];
#pragma unroll
      for (int nt = 0; nt < 4; ++nt)
        bfr[nt] = *(const bf16x8*)&Wlds[(nt * 16 + lr) * APITCH + lq * 8];
#pragma unroll
      for (int mt = 0; mt < 2; ++mt)
#pragma unroll
        for (int nt = 0; nt < 4; ++nt)
          acc[mt][nt] = __builtin_amdgcn_mfma_f32_16x16x32_bf16(
              af[mt], bfr[nt], acc[mt][nt], 0, 0, 0);
    }
    // transposed partial: gatesT[kz][gn][b]
    float* Cf = gatesT + (long)kz * 4 * HH * 128;
#pragma unroll
    for (int mt = 0; mt < 2; ++mt) {
      int gm = w * 32 + mt * 16 + lq * 4;
#pragma unroll
      for (int nt = 0; nt < 4; ++nt) {
        int gn = bn + nt * 16 + lr;
        float bv = (kz == 0) ? biasc[gn] : 0.f;
#pragma unroll
        for (int i = 0; i < 4; ++i)
          Cf[(long)gn * 128 + gm + i] = acc[mt][nt][i] + bv;
      }
    }
  } else {
    if (!do_fc2) return;
    int bn = (blk - 32 * KZ) * 64;
    const bf16* pa0 = out2 + (long)srow * 256 + skq;
    const bf16* pa1 = pa0 + (long)64 * 256;
    const bf16* pw = fc2w + (long)(bn + srow) * 256 + skq;
    bool wok = (bn + srow) < VV;
    f32x4 acc[2][4] = {};
    uint4 ra0 = *(const uint4*)pa0;
    uint4 ra1 = *(const uint4*)pa1;
    uint4 rw = wok ? *(const uint4*)pw : make_uint4(0, 0, 0, 0);
    for (int k0 = 0; k0 < 256; k0 += 32) {
      __syncthreads();
      *(uint4*)&Alds[srow * APITCH + skq] = ra0;
      *(uint4*)&Alds[(srow + 64) * APITCH + skq] = ra1;
      *(uint4*)&Wlds[srow * APITCH + skq] = rw;
      if (k0 + 32 < 256) {
        ra0 = *(const uint4*)(pa0 + k0 + 32);
        ra1 = *(const uint4*)(pa1 + k0 + 32);
        rw = wok ? *(const uint4*)(pw + k0 + 32) : make_uint4(0, 0, 0, 0);
      }
      __syncthreads();
      bf16x8 af[2], bfr[4];
#pragma unroll
      for (int mt = 0; mt < 2; ++mt)
        af[mt] = *(const bf16x8*)&Alds[(w * 32 + mt * 16 + lr) * APITCH + lq * 8];
#pragma unroll
      for (int nt = 0; nt < 4; ++nt)
        bfr[nt] = *(const bf16x8*)&Wlds[(nt * 16 + lr) * APITCH + lq * 8];
#pragma unroll
      for (int mt = 0; mt < 2; ++mt)
#pragma unroll
        for (int nt = 0; nt < 4; ++nt)
          acc[mt][nt] = __builtin_amdgcn_mfma_f32_16x16x32_bf16(
              af[mt], bfr[nt], acc[mt][nt], 0, 0, 0);
    }
    const long ldc = (long)TT * VV;
#pragma unroll
    for (int mt = 0; mt < 2; ++mt) {
      int gm = w * 32 + mt * 16 + lq * 4;
#pragma unroll
      for (int nt = 0; nt < 4; ++nt) {
        int gn = bn + nt * 16 + lr;
        if (gn >= VV) continue;
        float bv = fc2b[gn];
#pragma unroll
        for (int i = 0; i < 4; ++i)
          outp[(long)(gm + i) * ldc + gn] = acc[mt][nt][i] + bv;
      }
    }
  }
}

// ================= K1: LSTM pointwise + BN1 (transposed gates, coalesced)
__global__ __launch_bounds__(256) void lstm_bn2(
    const float* __restrict__ gatesT, float* __restrict__ cT,
    bf16* __restrict__ hbf, bf16* __restrict__ xnext,
    const float* __restrict__ g1, const float* __restrict__ be1) {
  int tid = threadIdx.x;
  int b = tid & 127, sub = tid >> 7;
  int ch = blockIdx.x * 2 + sub;
  const long GP = (long)4 * HH * 128;
  float vi = 0.f, vf = 0.f, vg = 0.f, vo = 0.f;
#pragma unroll
  for (int z = 0; z < KZ; ++z) {
    const float* gz = gatesT + z * GP + (long)ch * 128 + b;
    vi += gz[0 * HH * 128];
    vf += gz[1 * HH * 128];
    vg += gz[2 * HH * 128];
    vo += gz[3 * HH * 128];
  }
  float ig = sigmoidf(vi), fg = sigmoidf(vf), gg = tanh_fast(vg), og = sigmoidf(vo);
  float cn = fg * cT[ch * 128 + b] + ig * gg;
  cT[ch * 128 + b] = cn;
  float hr = og * tanh_fast(cn);
  __shared__ float s1[2][128];
  s1[sub][b] = hr;
  __syncthreads();
  for (int off = 64; off > 0; off >>= 1) {
    if (b < off) s1[sub][b] += s1[sub][b + off];
    __syncthreads();
  }
  float mean = s1[sub][0] * (1.f / 128);
  __syncthreads();
  float dv = hr - mean;
  s1[sub][b] = dv * dv;
  __syncthreads();
  for (int off = 64; off > 0; off >>= 1) {
    if (b < off) s1[sub][b] += s1[sub][b + off];
    __syncthreads();
  }
  float var = s1[sub][0] * (1.f / 128);
  float res = dv * (1.f / sqrtf(var + EPSV)) * g1[ch] + be1[ch];
  hbf[(long)b * HH + ch] = f2b(res);
  xnext[(long)b * XW + EE + DD + ch] = f2b(res);
}

extern "C" void kernel_launch(void* const* d_in, const int* in_sizes, int n_in,
                              void* d_out, int out_size, void* d_ws, size_t ws_size,
                              hipStream_t stream) {
  const int* captions  = (const int*)d_in[0];
  const float* features = (const float*)d_in[1];
  const float* emb   = (const float*)d_in[2];
  const float* Wa    = (const float*)d_in[3];
  const float* ba    = (const float*)d_in[4];
  const float* Ua    = (const float*)d_in[5];
  const float* bu    = (const float*)d_in[6];
  const float* va    = (const float*)d_in[7];
  const float* bv    = (const float*)d_in[8];
  const float* W_ih  = (const float*)d_in[9];
  const float* b_ih  = (const float*)d_in[10];
  const float* W_hh  = (const float*)d_in[11];
  const float* b_hh  = (const float*)d_in[12];
  const float* g1    = (const float*)d_in[13];
  const float* be1   = (const float*)d_in[14];
  const float* fc_w  = (const float*)d_in[15];
  const float* fc_b  = (const float*)d_in[16];
  const float* g2    = (const float*)d_in[17];
  const float* be2   = (const float*)d_in[18];
  const float* fc2_w = (const float*)d_in[19];
  const float* fc2_b = (const float*)d_in[20];
  const float* ih_w  = (const float*)d_in[21];
  const float* ih_b  = (const float*)d_in[22];
  const float* ic_w  = (const float*)d_in[23];
  const float* ic_b  = (const float*)d_in[24];

  float* out = (float*)d_out;                 // [B,T,V]
  float* att_out = out + (long)BQ * TT * VV;  // [B,T,R]

  char* p = (char*)d_ws;
  auto alloc = [&](size_t bytes) { char* r = p; p += (bytes + 255) & ~255ULL; return r; };
  bf16* featbf = (bf16*)alloc((size_t)BQ * RR * DD * 2);
  bf16* meanbf = (bf16*)alloc((size_t)BQ * DD * 2);
  bf16* Wcat   = (bf16*)alloc((size_t)4 * HH * XW * 2);
  bf16* Wabf   = (bf16*)alloc((size_t)HH * DD * 2);
  bf16* UaTbf  = (bf16*)alloc((size_t)HH * HH * 2);
  bf16* fcwbf  = (bf16*)alloc((size_t)256 * HH * 2);
  bf16* fc2wbf = (bf16*)alloc((size_t)VV * 256 * 2);
  bf16* ihwbf  = (bf16*)alloc((size_t)HH * DD * 2);
  bf16* icwbf  = (bf16*)alloc((size_t)HH * DD * 2);
  bf16* att1bf = (bf16*)alloc((size_t)BQ * RR * HH * 2);
  bf16* xcat_all = (bf16*)alloc((size_t)(TT + 1) * BQ * XW * 2);
  bf16* hbf    = (bf16*)alloc((size_t)BQ * HH * 2);
  bf16* out2bf = (bf16*)alloc((size_t)BQ * 256 * 2);
  float* biasc = (float*)alloc((size_t)4 * HH * 4);
  float* cT    = (float*)alloc((size_t)BQ * HH * 4);
  float* gatesT = (float*)alloc((size_t)KZ * BQ * 4 * HH * 4);  // KZ split-K partials, [gn][b]

  // ---- prologue ----
  f2b_kernel<<<(BQ * RR * DD / 4 + 255) / 256, 256, 0, stream>>>(features, featbf, BQ * RR * DD / 4);
  f2b_kernel<<<(HH * DD / 4 + 255) / 256, 256, 0, stream>>>(Wa, Wabf, HH * DD / 4);
  transpose_ua<<<dim3(8, 8), 256, 0, stream>>>(Ua, UaTbf);
  f2b_kernel<<<(256 * HH / 4 + 255) / 256, 256, 0, stream>>>(fc_w, fcwbf, 256 * HH / 4);
  f2b_kernel<<<(VV * 256 / 4 + 255) / 256, 256, 0, stream>>>(fc2_w, fc2wbf, VV * 256 / 4);
  f2b_kernel<<<(HH * DD / 4 + 255) / 256, 256, 0, stream>>>(ih_w, ihwbf, HH * DD / 4);
  f2b_kernel<<<(HH * DD / 4 + 255) / 256, 256, 0, stream>>>(ic_w, icwbf, HH * DD / 4);
  wcat_kernel<<<dim3(XW / 4 / 256, 4 * HH), 256, 0, stream>>>(W_ih, W_hh, Wcat);
  biasc_kernel<<<(4 * HH + 255) / 256, 256, 0, stream>>>(b_ih, b_hh, biasc);
  mean_kernel<<<(BQ * DD + 255) / 256, 256, 0, stream>>>(featbf, meanbf);
  embed_all_kernel<<<(BQ * TT * EE / 4) / 256, 256, 0, stream>>>(captions, emb, xcat_all);

  // h0 -> hbf + xcat_0 h-slice; c0 -> cT (fp32, transposed [ch][b])
  gemm_mfma<<<dim3(HH / 64, 1), 256, 0, stream>>>(
      meanbf, ihwbf, ih_b, nullptr, hbf, xcat_all + EE + DD, HH, XW, HH, DD, 0, 0);
  gemm_mfma<<<dim3(HH / 64, 1), 256, 0, stream>>>(
      meanbf, icwbf, ic_b, cT, nullptr, nullptr, 128, 0, HH, DD, 0, 1);
  // att1 = features @ Wa^T + ba  (bf16 out)
  gemm_mfma<<<dim3(HH / 64, BQ * RR / 128), 256, 0, stream>>>(
      featbf, Wabf, ba, nullptr, att1bf, nullptr, HH, 0, HH, DD, 0, 0);

  // ---- timestep loop: 3 kernels/step ----
  for (int t = 0; t < TT; ++t) {
    bf16* xc = xcat_all + (size_t)t * BQ * XW;
    bf16* xn = xcat_all + (size_t)(t + 1) * BQ * XW;
    // attn(t) || fc1+bn2 on h(t-1)
    step_attn_fc<<<160, 512, 0, stream>>>(
        att1bf, hbf, UaTbf, bu, va, bv, featbf, xc, att_out, t, 1,
        fcwbf, fc_b, g2, be2, out2bf, t > 0 ? 1 : 0);
    // gates(t) || fc2(t-1)
    step_gemms<<<32 * KZ + 157, 256, 0, stream>>>(
        xc, Wcat, biasc, gatesT, out2bf, fc2wbf, fc2_b,
        out + (long)(t > 0 ? t - 1 : 0) * VV, 1, t > 0 ? 1 : 0);
    // lstm + bn1 -> h(t)
    lstm_bn2<<<HH / 2, 256, 0, stream>>>(gatesT, cT, hbf, xn, g1, be1);
  }
  // tail: fc1+bn2 and fc2 for t = TT-1
  step_attn_fc<<<160, 512, 0, stream>>>(
      att1bf, hbf, UaTbf, bu, va, bv, featbf, xcat_all, att_out, 0, 0,
      fcwbf, fc_b, g2, be2, out2bf, 1);
  step_gemms<<<32 * KZ + 157, 256, 0, stream>>>(
      xcat_all, Wcat, biasc, gatesT, out2bf, fc2wbf, fc2_b,
      out + (long)(TT - 1) * VV, 0, 1);
}

// Round 6
// 1347.681 us; speedup vs baseline: 1.3429x; 1.0660x over previous
//
#include <hip/hip_runtime.h>
#include <hip/hip_bf16.h>
#include <math.h>

typedef __hip_bfloat16 bf16;
typedef short bf16x8 __attribute__((ext_vector_type(8)));
typedef float f32x4 __attribute__((ext_vector_type(4)));

#define BQ 128   // batch
#define TT 20    // timesteps
#define RR 49    // regions
#define DD 2048  // feature dim
#define EE 512   // embed dim
#define HH 512   // hidden
#define VV 10000 // vocab
#define XW 3072  // xcat width = E + D + H
constexpr float EPSV = 1e-5f;
#define APITCH 40  // LDS row pitch in bf16 elems (80B) — breaks pow2 bank stride
#define KZ 8       // gates split-K depth

__device__ __forceinline__ float sigmoidf(float x) { return 1.f / (1.f + __expf(-x)); }
__device__ __forceinline__ float tanh_fast(float x) {
  float e = __expf(2.f * x);
  return 1.f - 2.f / (e + 1.f);
}
__device__ __forceinline__ bf16 f2b(float v) { return __float2bfloat16(v); }
__device__ __forceinline__ float b2f(bf16 v) { return __bfloat162float(v); }

// ---------------- fused elementwise prologue ----------------
// segment block counts
#define NB_FEAT 12544  // features f2b: 128*49*2048/4/256
#define NB_WA   1024   // Wa f2b: 512*2048/4/256
#define NB_FCW  128    // fc_w f2b
#define NB_FC2W 2500   // fc2_w f2b: 10000*256/4/256
#define NB_IHW  1024
#define NB_ICW  1024
#define NB_WCAT 6144   // 2048 rows x 3 col-chunks
#define NB_BIAS 8
#define NB_EMB  1280   // 128*20*512/4/256
#define NB_TUA  64     // 8x8 tiles
#define NB_MEAN 1024   // 128*2048/256
#define NB_TOTAL (NB_FEAT+NB_WA+NB_FCW+NB_FC2W+NB_IHW+NB_ICW+NB_WCAT+NB_BIAS+NB_EMB+NB_TUA+NB_MEAN)

__device__ __forceinline__ void f2b4(const float* __restrict__ src,
                                     bf16* __restrict__ dst, long i) {
  float4 v = ((const float4*)src)[i];
  bf16 o[4] = {f2b(v.x), f2b(v.y), f2b(v.z), f2b(v.w)};
  *(ushort4*)(dst + i * 4) = *(const ushort4*)o;
}

__global__ __launch_bounds__(256) void fused_prep(
    const float* __restrict__ features, const float* __restrict__ Wa,
    const float* __restrict__ fc_w, const float* __restrict__ fc2_w,
    const float* __restrict__ ih_w, const float* __restrict__ ic_w,
    const float* __restrict__ W_ih, const float* __restrict__ W_hh,
    const float* __restrict__ b_ih, const float* __restrict__ b_hh,
    const int* __restrict__ cap, const float* __restrict__ emb,
    const float* __restrict__ Ua,
    bf16* __restrict__ featbf, bf16* __restrict__ Wabf, bf16* __restrict__ fcwbf,
    bf16* __restrict__ fc2wbf, bf16* __restrict__ ihwbf, bf16* __restrict__ icwbf,
    bf16* __restrict__ Wcat, float* __restrict__ biasc, bf16* __restrict__ xcat_all,
    bf16* __restrict__ UaTbf, bf16* __restrict__ meanbf) {
  __shared__ float tile[64][65];
  int bid = blockIdx.x, tid = threadIdx.x;
  if (bid < NB_FEAT) { f2b4(features, featbf, (long)bid * 256 + tid); return; }
  bid -= NB_FEAT;
  if (bid < NB_WA) { f2b4(Wa, Wabf, (long)bid * 256 + tid); return; }
  bid -= NB_WA;
  if (bid < NB_FCW) { f2b4(fc_w, fcwbf, (long)bid * 256 + tid); return; }
  bid -= NB_FCW;
  if (bid < NB_FC2W) { f2b4(fc2_w, fc2wbf, (long)bid * 256 + tid); return; }
  bid -= NB_FC2W;
  if (bid < NB_IHW) { f2b4(ih_w, ihwbf, (long)bid * 256 + tid); return; }
  bid -= NB_IHW;
  if (bid < NB_ICW) { f2b4(ic_w, icwbf, (long)bid * 256 + tid); return; }
  bid -= NB_ICW;
  if (bid < NB_WCAT) {
    int n = bid / 3, xp = bid - n * 3;
    int kc = (xp * 256 + tid) * 4;
    float4 v = (kc < EE + DD) ? *(const float4*)(W_ih + (long)n * (EE + DD) + kc)
                              : *(const float4*)(W_hh + (long)n * HH + (kc - EE - DD));
    bf16 o[4] = {f2b(v.x), f2b(v.y), f2b(v.z), f2b(v.w)};
    *(ushort4*)(Wcat + (long)n * XW + kc) = *(const ushort4*)o;
    return;
  }
  bid -= NB_WCAT;
  if (bid < NB_BIAS) {
    int i = bid * 256 + tid;
    biasc[i] = b_ih[i] + b_hh[i];
    return;
  }
  bid -= NB_BIAS;
  if (bid < NB_EMB) {
    long idx = (long)bid * 256 + tid;
    int bt = (int)(idx >> 7);
    int e4 = ((int)idx & 127) * 4;
    int b = bt / TT, t = bt - b * TT;
    int tok = cap[b * TT + t];
    float4 v = *(const float4*)(emb + (long)tok * EE + e4);
    bf16 o[4] = {f2b(v.x), f2b(v.y), f2b(v.z), f2b(v.w)};
    *(ushort4*)(xcat_all + ((long)t * BQ + b) * XW + e4) = *(const ushort4*)o;
    return;
  }
  bid -= NB_EMB;
  if (bid < NB_TUA) {
    int tx = tid & 63, ty = tid >> 6;
    int c0 = (bid & 7) * 64, k0 = (bid >> 3) * 64;
    for (int r = ty; r < 64; r += 4)
      tile[r][tx] = Ua[(long)(c0 + r) * HH + k0 + tx];
    __syncthreads();
    for (int r = ty; r < 64; r += 4)
      UaTbf[(long)(k0 + r) * HH + c0 + tx] = f2b(tile[tx][r]);
    return;
  }
  bid -= NB_TUA;
  {  // mean over R regions, fp32 input (no intra-dispatch dependency)
    int idx = bid * 256 + tid;
    int b = idx >> 11, d = idx & (DD - 1);
    const float* p = features + (long)b * RR * DD + d;
    float s = 0.f;
    for (int r = 0; r < RR; ++r) s += p[(long)r * DD];
    meanbf[idx] = f2b(s * (1.f / RR));
  }
}

// ---------------- shared MFMA tile body (128x64 tile, both strides = K) ---
__device__ __forceinline__ void mfma_tile(
    const bf16* __restrict__ A, const bf16* __restrict__ W, int K,
    int tid, short* Alds, short* Wlds, f32x4 (&acc)[2][4]) {
  int w = tid >> 6, l = tid & 63;
  int lr = l & 15, lq = l >> 4;
  int srow = tid >> 2, skq = (tid & 3) * 8;
  const bf16* pa0 = A + (long)srow * K + skq;
  const bf16* pa1 = pa0 + (long)64 * K;
  const bf16* pw = W + (long)srow * K + skq;
  uint4 ra0 = *(const uint4*)pa0;
  uint4 ra1 = *(const uint4*)pa1;
  uint4 rw = *(const uint4*)pw;
  for (int k0 = 0; k0 < K; k0 += 32) {
    __syncthreads();
    *(uint4*)&Alds[srow * APITCH + skq] = ra0;
    *(uint4*)&Alds[(srow + 64) * APITCH + skq] = ra1;
    *(uint4*)&Wlds[srow * APITCH + skq] = rw;
    if (k0 + 32 < K) {
      ra0 = *(const uint4*)(pa0 + k0 + 32);
      ra1 = *(const uint4*)(pa1 + k0 + 32);
      rw = *(const uint4*)(pw + k0 + 32);
    }
    __syncthreads();
    bf16x8 af[2], bfr[4];
#pragma unroll
    for (int mt = 0; mt < 2; ++mt)
      af[mt] = *(const bf16x8*)&Alds[(w * 32 + mt * 16 + lr) * APITCH + lq * 8];
#pragma unroll
    for (int nt = 0; nt < 4; ++nt)
      bfr[nt] = *(const bf16x8*)&Wlds[(nt * 16 + lr) * APITCH + lq * 8];
#pragma unroll
    for (int mt = 0; mt < 2; ++mt)
#pragma unroll
      for (int nt = 0; nt < 4; ++nt)
        acc[mt][nt] = __builtin_amdgcn_mfma_f32_16x16x32_bf16(
            af[mt], bfr[nt], acc[mt][nt], 0, 0, 0);
  }
}

// ---------------- fused prologue GEMMs: h0 [0..7] || c0 [8..15] || att1 [16..407]
__global__ __launch_bounds__(256) void prol_gemms(
    const bf16* __restrict__ meanbf, const bf16* __restrict__ ihwbf,
    const bf16* __restrict__ icwbf, const float* __restrict__ ih_b,
    const float* __restrict__ ic_b, const bf16* __restrict__ featbf,
    const bf16* __restrict__ Wabf, const float* __restrict__ ba,
    bf16* __restrict__ hbf, bf16* __restrict__ xcat0h,
    float* __restrict__ cT, bf16* __restrict__ att1bf) {
  __shared__ __align__(16) short Alds[128 * APITCH];
  __shared__ __align__(16) short Wlds[64 * APITCH];
  int blk = blockIdx.x, tid = threadIdx.x;
  int w = tid >> 6, l = tid & 63, lr = l & 15, lq = l >> 4;
  f32x4 acc[2][4] = {};
  if (blk < 8) {
    int bn = blk * 64;
    mfma_tile(meanbf, ihwbf + (long)bn * DD, DD, tid, Alds, Wlds, acc);
#pragma unroll
    for (int mt = 0; mt < 2; ++mt) {
      int gm = w * 32 + mt * 16 + lq * 4;
#pragma unroll
      for (int nt = 0; nt < 4; ++nt) {
        int gn = bn + nt * 16 + lr;
        float bv = ih_b[gn];
#pragma unroll
        for (int i = 0; i < 4; ++i) {
          bf16 r = f2b(acc[mt][nt][i] + bv);
          hbf[(long)(gm + i) * HH + gn] = r;
          xcat0h[(long)(gm + i) * XW + gn] = r;
        }
      }
    }
  } else if (blk < 16) {
    int bn = (blk - 8) * 64;
    mfma_tile(meanbf, icwbf + (long)bn * DD, DD, tid, Alds, Wlds, acc);
#pragma unroll
    for (int mt = 0; mt < 2; ++mt) {
      int gm = w * 32 + mt * 16 + lq * 4;
#pragma unroll
      for (int nt = 0; nt < 4; ++nt) {
        int gn = bn + nt * 16 + lr;
        float bv = ic_b[gn];
#pragma unroll
        for (int i = 0; i < 4; ++i)
          cT[(long)gn * 128 + gm + i] = acc[mt][nt][i] + bv;
      }
    }
  } else {
    int tt = blk - 16;
    int bmt = tt >> 3, bn = (tt & 7) * 64;
    mfma_tile(featbf + (long)bmt * 128 * DD, Wabf + (long)bn * DD, DD,
              tid, Alds, Wlds, acc);
#pragma unroll
    for (int mt = 0; mt < 2; ++mt) {
      int gm = w * 32 + mt * 16 + lq * 4;
#pragma unroll
      for (int nt = 0; nt < 4; ++nt) {
        int gn = bn + nt * 16 + lr;
        float bv = ba[gn];
#pragma unroll
        for (int i = 0; i < 4; ++i)
          att1bf[(long)(bmt * 128 + gm + i) * HH + gn] = f2b(acc[mt][nt][i] + bv);
      }
    }
  }
}

// ================= K2: attn(t) [blocks 0..127] || fc1+BN2(t-1) [blocks 128..159]
__global__ __launch_bounds__(512) void step_attn_fc(
    const bf16* __restrict__ att1, const bf16* __restrict__ hbf,
    const bf16* __restrict__ UaT, const float* __restrict__ bu,
    const float* __restrict__ va, const float* __restrict__ bv,
    const bf16* __restrict__ feat, bf16* __restrict__ xcat,
    float* __restrict__ att_out, int t, int do_attn,
    const bf16* __restrict__ fcw, const float* __restrict__ fcb,
    const float* __restrict__ g2, const float* __restrict__ be2,
    bf16* __restrict__ out2, int do_fc) {
  __shared__ __align__(16) char smem[29824];
  int blk = blockIdx.x, tid = threadIdx.x;
  if (blk < 128) {
    // ---------- attention segment ----------
    if (!do_attn) return;
    int b = blk;
    float* hs = (float*)smem;        // 512
    float* vas = hs + 512;           // 512
    float* a2s = vas + 512;          // 512
    float* a2p = a2s + 512;          // 1024
    float* sc = a2p + 1024;          // 64
    hs[tid] = b2f(hbf[b * HH + tid]);
    vas[tid] = va[tid];
    __syncthreads();
    // a2 = h @ Ua^T + bu, split over k-halves: tid<256 -> k[0,256), else k[256,512)
    {
      int half = tid >> 8, cp = (tid & 255) * 2;
      const bf16* up = UaT + (long)(half * 256) * HH + cp;
      const float* hh = hs + half * 256;
      float a0 = 0.f, a1 = 0.f;
#pragma unroll 8
      for (int k = 0; k < 256; ++k) {
        uint u = *(const uint*)(up + (long)k * HH);
        float hk = hh[k];
        a0 += hk * b2f(((const bf16*)&u)[0]);
        a1 += hk * b2f(((const bf16*)&u)[1]);
      }
      a2p[half * 512 + cp] = a0;
      a2p[half * 512 + cp + 1] = a1;
    }
    __syncthreads();
    if (tid < 256) {
      int ch = tid * 2;
      a2s[ch] = a2p[ch] + a2p[512 + ch] + bu[ch];
      a2s[ch + 1] = a2p[ch + 1] + a2p[512 + ch + 1] + bu[ch + 1];
    }
    __syncthreads();
    int wave = tid >> 6, lane = tid & 63;
    float vreg[8], areg[8];
    *(float4*)&vreg[0] = *(const float4*)&vas[lane * 8];
    *(float4*)&vreg[4] = *(const float4*)&vas[lane * 8 + 4];
    *(float4*)&areg[0] = *(const float4*)&a2s[lane * 8];
    *(float4*)&areg[4] = *(const float4*)&a2s[lane * 8 + 4];
    for (int r = wave; r < RR; r += 8) {
      bf16 rv[8];
      *(uint4*)rv = *(const uint4*)(att1 + ((long)b * RR + r) * HH + lane * 8);
      float p = 0.f;
#pragma unroll
      for (int j = 0; j < 8; ++j)
        p += vreg[j] * tanh_fast(b2f(rv[j]) + areg[j]);
#pragma unroll
      for (int off = 32; off > 0; off >>= 1) p += __shfl_down(p, off, 64);
      if (lane == 0) sc[r] = p + bv[0];
    }
    __syncthreads();
    if (tid < 64) {
      float v = (tid < RR) ? sc[tid] : -1e30f;
      float m = v;
#pragma unroll
      for (int off = 32; off > 0; off >>= 1) m = fmaxf(m, __shfl_xor(m, off, 64));
      float e = (tid < RR) ? __expf(v - m) : 0.f;
      float s = e;
#pragma unroll
      for (int off = 32; off > 0; off >>= 1) s += __shfl_xor(s, off, 64);
      float wgt = e / s;
      if (tid < RR) {
        sc[tid] = wgt;
        att_out[((long)b * TT + t) * RR + tid] = wgt;
      }
    }
    __syncthreads();
    // ctx: 512 threads x 4 d's
    const bf16* fb = feat + (long)b * RR * DD + tid * 4;
    float ac[4] = {};
    for (int r = 0; r < RR; ++r) {
      uint2 u = *(const uint2*)(fb + (long)r * DD);
      const bf16* pv = (const bf16*)&u;
      float wr = sc[r];
#pragma unroll
      for (int j = 0; j < 4; ++j) ac[j] += wr * b2f(pv[j]);
    }
    bf16 ov[4];
#pragma unroll
    for (int j = 0; j < 4; ++j) ov[j] = f2b(ac[j]);
    *(uint2*)(xcat + (long)b * XW + EE + tid * 4) = *(const uint2*)ov;
  } else {
    // ---------- fc1 + ReLU + BN2 segment ----------
    if (!do_fc) return;
    int ch0 = (blk - 128) * 8;
    short* wlds = (short*)smem;              // 8*512 = 4096 shorts
    short* hlds = wlds + 4096;               // 128 rows x 68 pitch
    float* red = (float*)(smem + (4096 + 8704) * 2);  // [8][130]
    float* stat = red + 8 * 130;
    const int HP = 68;
    *(bf16x8*)&wlds[tid * 8] = *(const bf16x8*)(fcw + (long)ch0 * HH + tid * 8);
    int b = tid & 127, cg = tid >> 7;
    float acc2[2] = {0.f, 0.f};
    int srow = tid >> 3, sc8 = (tid & 7) * 8;
    for (int k0 = 0; k0 < HH; k0 += 64) {
      __syncthreads();
      *(uint4*)&hlds[srow * HP + sc8] =
          *(const uint4*)(hbf + (long)srow * HH + k0 + sc8);
      *(uint4*)&hlds[(srow + 64) * HP + sc8] =
          *(const uint4*)(hbf + (long)(srow + 64) * HH + k0 + sc8);
      __syncthreads();
#pragma unroll
      for (int kk = 0; kk < 64; kk += 8) {
        bf16 hv[8];
        *(uint4*)hv = *(const uint4*)&hlds[b * HP + kk];
        float hf[8];
#pragma unroll
        for (int j = 0; j < 8; ++j) hf[j] = b2f(hv[j]);
#pragma unroll
        for (int jc = 0; jc < 2; ++jc) {
          const bf16* wr = (const bf16*)&wlds[(cg * 2 + jc) * 512 + k0 + kk];
#pragma unroll
          for (int j = 0; j < 8; ++j) acc2[jc] += hf[j] * b2f(wr[j]);
        }
      }
    }
    float val2[2], dv2[2];
#pragma unroll
    for (int jc = 0; jc < 2; ++jc) {
      int cl = cg * 2 + jc;
      val2[jc] = fmaxf(acc2[jc] + fcb[ch0 + cl], 0.f);
      red[cl * 130 + b] = val2[jc];
    }
    __syncthreads();
    if (tid < 8) {
      float s = 0.f;
      for (int i = 0; i < 128; i += 4)
        s += red[tid * 130 + i] + red[tid * 130 + i + 1] +
             red[tid * 130 + i + 2] + red[tid * 130 + i + 3];
      stat[tid] = s * (1.f / 128);
    }
    __syncthreads();
#pragma unroll
    for (int jc = 0; jc < 2; ++jc) {
      int cl = cg * 2 + jc;
      dv2[jc] = val2[jc] - stat[cl];
      red[cl * 130 + b] = dv2[jc] * dv2[jc];
    }
    __syncthreads();
    if (tid < 8) {
      float s = 0.f;
      for (int i = 0; i < 128; i += 4)
        s += red[tid * 130 + i] + red[tid * 130 + i + 1] +
             red[tid * 130 + i + 2] + red[tid * 130 + i + 3];
      stat[tid] = 1.f / sqrtf(s * (1.f / 128) + EPSV);
    }
    __syncthreads();
#pragma unroll
    for (int jc = 0; jc < 2; ++jc) {
      int cl = cg * 2 + jc;
      out2[(long)b * 256 + ch0 + cl] =
          f2b(dv2[jc] * stat[cl] * g2[ch0 + cl] + be2[ch0 + cl]);
    }
  }
}

// ================= K3: gates GEMM split-K x8 [blocks 0..255] || fc2 [256..412]
__global__ __launch_bounds__(256) void step_gemms(
    const bf16* __restrict__ xc, const bf16* __restrict__ Wcat,
    const float* __restrict__ biasc, float* __restrict__ gatesT,
    const bf16* __restrict__ out2, const bf16* __restrict__ fc2w,
    const float* __restrict__ fc2b, float* __restrict__ outp,
    int do_gates, int do_fc2) {
  __shared__ __align__(16) short Alds[128 * APITCH];
  __shared__ __align__(16) short Wlds[64 * APITCH];
  int blk = blockIdx.x, tid = threadIdx.x;
  int w = tid >> 6, l = tid & 63;
  int lr = l & 15, lq = l >> 4;
  int srow = tid >> 2, skq = (tid & 3) * 8;
  if (blk < 32 * KZ) {
    if (!do_gates) return;
    const int KC = XW / KZ;  // 384
    int tile = blk & 31, kz = blk >> 5;
    int bn = tile * 64, kbeg = kz * KC;
    const bf16* pa0 = xc + (long)srow * XW + kbeg + skq;
    const bf16* pa1 = pa0 + (long)64 * XW;
    const bf16* pw = Wcat + (long)(bn + srow) * XW + kbeg + skq;
    f32x4 acc[2][4] = {};
    uint4 ra0 = *(const uint4*)pa0;
    uint4 ra1 = *(const uint4*)pa1;
    uint4 rw = *(const uint4*)pw;
    for (int k0 = 0; k0 < KC; k0 += 32) {
      __syncthreads();
      *(uint4*)&Alds[srow * APITCH + skq] = ra0;
      *(uint4*)&Alds[(srow + 64) * APITCH + skq] = ra1;
      *(uint4*)&Wlds[srow * APITCH + skq] = rw;
      if (k0 + 32 < KC) {
        ra0 = *(const uint4*)(pa0 + k0 + 32);
        ra1 = *(const uint4*)(pa1 + k0 + 32);
        rw = *(const uint4*)(pw + k0 + 32);
      }
      __syncthreads();
      bf16x8 af[2], bfr[4];
#pragma unroll
      for (int mt = 0; mt < 2; ++mt)
        af[mt] = *(const bf16x8*)&Alds[(w * 32 + mt * 16 + lr) * APITCH + lq * 8];
#pragma unroll
      for (int nt = 0; nt < 4; ++nt)
        bfr[nt] = *(const bf16x8*)&Wlds[(nt * 16 + lr) * APITCH + lq * 8];
#pragma unroll
      for (int mt = 0; mt < 2; ++mt)
#pragma unroll
        for (int nt = 0; nt < 4; ++nt)
          acc[mt][nt] = __builtin_amdgcn_mfma_f32_16x16x32_bf16(
              af[mt], bfr[nt], acc[mt][nt], 0, 0, 0);
    }
    float* Cf = gatesT + (long)kz * 4 * HH * 128;
#pragma unroll
    for (int mt = 0; mt < 2; ++mt) {
      int gm = w * 32 + mt * 16 + lq * 4;
#pragma unroll
      for (int nt = 0; nt < 4; ++nt) {
        int gn = bn + nt * 16 + lr;
        float bv = (kz == 0) ? biasc[gn] : 0.f;
#pragma unroll
        for (int i = 0; i < 4; ++i)
          Cf[(long)gn * 128 + gm + i] = acc[mt][nt][i] + bv;
      }
    }
  } else {
    if (!do_fc2) return;
    int bn = (blk - 32 * KZ) * 64;
    const bf16* pa0 = out2 + (long)srow * 256 + skq;
    const bf16* pa1 = pa0 + (long)64 * 256;
    const bf16* pw = fc2w + (long)(bn + srow) * 256 + skq;
    bool wok = (bn + srow) < VV;
    f32x4 acc[2][4] = {};
    uint4 ra0 = *(const uint4*)pa0;
    uint4 ra1 = *(const uint4*)pa1;
    uint4 rw = wok ? *(const uint4*)pw : make_uint4(0, 0, 0, 0);
    for (int k0 = 0; k0 < 256; k0 += 32) {
      __syncthreads();
      *(uint4*)&Alds[srow * APITCH + skq] = ra0;
      *(uint4*)&Alds[(srow + 64) * APITCH + skq] = ra1;
      *(uint4*)&Wlds[srow * APITCH + skq] = rw;
      if (k0 + 32 < 256) {
        ra0 = *(const uint4*)(pa0 + k0 + 32);
        ra1 = *(const uint4*)(pa1 + k0 + 32);
        rw = wok ? *(const uint4*)(pw + k0 + 32) : make_uint4(0, 0, 0, 0);
      }
      __syncthreads();
      bf16x8 af[2], bfr[4];
#pragma unroll
      for (int mt = 0; mt < 2; ++mt)
        af[mt] = *(const bf16x8*)&Alds[(w * 32 + mt * 16 + lr) * APITCH + lq * 8];
#pragma unroll
      for (int nt = 0; nt < 4; ++nt)
        bfr[nt] = *(const bf16x8*)&Wlds[(nt * 16 + lr) * APITCH + lq * 8];
#pragma unroll
      for (int mt = 0; mt < 2; ++mt)
#pragma unroll
        for (int nt = 0; nt < 4; ++nt)
          acc[mt][nt] = __builtin_amdgcn_mfma_f32_16x16x32_bf16(
              af[mt], bfr[nt], acc[mt][nt], 0, 0, 0);
    }
    const long ldc = (long)TT * VV;
#pragma unroll
    for (int mt = 0; mt < 2; ++mt) {
      int gm = w * 32 + mt * 16 + lq * 4;
#pragma unroll
      for (int nt = 0; nt < 4; ++nt) {
        int gn = bn + nt * 16 + lr;
        if (gn >= VV) continue;
        float bv = fc2b[gn];
#pragma unroll
        for (int i = 0; i < 4; ++i)
          outp[(long)(gm + i) * ldc + gn] = acc[mt][nt][i] + bv;
      }
    }
  }
}

// ================= K1: LSTM pointwise + BN1 (transposed gates, coalesced)
__global__ __launch_bounds__(256) void lstm_bn2(
    const float* __restrict__ gatesT, float* __restrict__ cT,
    bf16* __restrict__ hbf, bf16* __restrict__ xnext,
    const float* __restrict__ g1, const float* __restrict__ be1) {
  int tid = threadIdx.x;
  int b = tid & 127, sub = tid >> 7;
  int ch = blockIdx.x * 2 + sub;
  const long GP = (long)4 * HH * 128;
  float vi = 0.f, vf = 0.f, vg = 0.f, vo = 0.f;
#pragma unroll
  for (int z = 0; z < KZ; ++z) {
    const float* gz = gatesT + z * GP + (long)ch * 128 + b;
    vi += gz[0 * HH * 128];
    vf += gz[1 * HH * 128];
    vg += gz[2 * HH * 128];
    vo += gz[3 * HH * 128];
  }
  float ig = sigmoidf(vi), fg = sigmoidf(vf), gg = tanh_fast(vg), og = sigmoidf(vo);
  float cn = fg * cT[ch * 128 + b] + ig * gg;
  cT[ch * 128 + b] = cn;
  float hr = og * tanh_fast(cn);
  __shared__ float s1[2][128];
  s1[sub][b] = hr;
  __syncthreads();
  for (int off = 64; off > 0; off >>= 1) {
    if (b < off) s1[sub][b] += s1[sub][b + off];
    __syncthreads();
  }
  float mean = s1[sub][0] * (1.f / 128);
  __syncthreads();
  float dv = hr - mean;
  s1[sub][b] = dv * dv;
  __syncthreads();
  for (int off = 64; off > 0; off >>= 1) {
    if (b < off) s1[sub][b] += s1[sub][b + off];
    __syncthreads();
  }
  float var = s1[sub][0] * (1.f / 128);
  float res = dv * (1.f / sqrtf(var + EPSV)) * g1[ch] + be1[ch];
  hbf[(long)b * HH + ch] = f2b(res);
  xnext[(long)b * XW + EE + DD + ch] = f2b(res);
}

extern "C" void kernel_launch(void* const* d_in, const int* in_sizes, int n_in,
                              void* d_out, int out_size, void* d_ws, size_t ws_size,
                              hipStream_t stream) {
  const int* captions  = (const int*)d_in[0];
  const float* features = (const float*)d_in[1];
  const float* emb   = (const float*)d_in[2];
  const float* Wa    = (const float*)d_in[3];
  const float* ba    = (const float*)d_in[4];
  const float* Ua    = (const float*)d_in[5];
  const float* bu    = (const float*)d_in[6];
  const float* va    = (const float*)d_in[7];
  const float* bv    = (const float*)d_in[8];
  const float* W_ih  = (const float*)d_in[9];
  const float* b_ih  = (const float*)d_in[10];
  const float* W_hh  = (const float*)d_in[11];
  const float* b_hh  = (const float*)d_in[12];
  const float* g1    = (const float*)d_in[13];
  const float* be1   = (const float*)d_in[14];
  const float* fc_w  = (const float*)d_in[15];
  const float* fc_b  = (const float*)d_in[16];
  const float* g2    = (const float*)d_in[17];
  const float* be2   = (const float*)d_in[18];
  const float* fc2_w = (const float*)d_in[19];
  const float* fc2_b = (const float*)d_in[20];
  const float* ih_w  = (const float*)d_in[21];
  const float* ih_b  = (const float*)d_in[22];
  const float* ic_w  = (const float*)d_in[23];
  const float* ic_b  = (const float*)d_in[24];

  float* out = (float*)d_out;                 // [B,T,V]
  float* att_out = out + (long)BQ * TT * VV;  // [B,T,R]

  char* p = (char*)d_ws;
  auto alloc = [&](size_t bytes) { char* r = p; p += (bytes + 255) & ~255ULL; return r; };
  bf16* featbf = (bf16*)alloc((size_t)BQ * RR * DD * 2);
  bf16* meanbf = (bf16*)alloc((size_t)BQ * DD * 2);
  bf16* Wcat   = (bf16*)alloc((size_t)4 * HH * XW * 2);
  bf16* Wabf   = (bf16*)alloc((size_t)HH * DD * 2);
  bf16* UaTbf  = (bf16*)alloc((size_t)HH * HH * 2);
  bf16* fcwbf  = (bf16*)alloc((size_t)256 * HH * 2);
  bf16* fc2wbf = (bf16*)alloc((size_t)VV * 256 * 2);
  bf16* ihwbf  = (bf16*)alloc((size_t)HH * DD * 2);
  bf16* icwbf  = (bf16*)alloc((size_t)HH * DD * 2);
  bf16* att1bf = (bf16*)alloc((size_t)BQ * RR * HH * 2);
  bf16* xcat_all = (bf16*)alloc((size_t)(TT + 1) * BQ * XW * 2);
  bf16* hbf    = (bf16*)alloc((size_t)BQ * HH * 2);
  bf16* out2bf = (bf16*)alloc((size_t)BQ * 256 * 2);
  float* biasc = (float*)alloc((size_t)4 * HH * 4);
  float* cT    = (float*)alloc((size_t)BQ * HH * 4);
  float* gatesT = (float*)alloc((size_t)KZ * BQ * 4 * HH * 4);

  // ---- prologue: 2 dispatches ----
  fused_prep<<<NB_TOTAL, 256, 0, stream>>>(
      features, Wa, fc_w, fc2_w, ih_w, ic_w, W_ih, W_hh, b_ih, b_hh,
      captions, emb, Ua,
      featbf, Wabf, fcwbf, fc2wbf, ihwbf, icwbf, Wcat, biasc, xcat_all,
      UaTbf, meanbf);
  prol_gemms<<<408, 256, 0, stream>>>(
      meanbf, ihwbf, icwbf, ih_b, ic_b, featbf, Wabf, ba,
      hbf, xcat_all + EE + DD, cT, att1bf);

  // ---- timestep loop: 3 kernels/step ----
  for (int t = 0; t < TT; ++t) {
    bf16* xc = xcat_all + (size_t)t * BQ * XW;
    bf16* xn = xcat_all + (size_t)(t + 1) * BQ * XW;
    step_attn_fc<<<160, 512, 0, stream>>>(
        att1bf, hbf, UaTbf, bu, va, bv, featbf, xc, att_out, t, 1,
        fcwbf, fc_b, g2, be2, out2bf, t > 0 ? 1 : 0);
    step_gemms<<<32 * KZ + 157, 256, 0, stream>>>(
        xc, Wcat, biasc, gatesT, out2bf, fc2wbf, fc2_b,
        out + (long)(t > 0 ? t - 1 : 0) * VV, 1, t > 0 ? 1 : 0);
    lstm_bn2<<<HH / 2, 256, 0, stream>>>(gatesT, cT, hbf, xn, g1, be1);
  }
  // tail: fc1+bn2 and fc2 for t = TT-1
  step_attn_fc<<<160, 512, 0, stream>>>(
      att1bf, hbf, UaTbf, bu, va, bv, featbf, xcat_all, att_out, 0, 0,
      fcwbf, fc_b, g2, be2, out2bf, 1);
  step_gemms<<<32 * KZ + 157, 256, 0, stream>>>(
      xcat_all, Wcat, biasc, gatesT, out2bf, fc2wbf, fc2_b,
      out + (long)(TT - 1) * VV, 0, 1);
}